// Round 13
// baseline (561.439 us; speedup 1.0000x reference)
//
#include <hip/hip_runtime.h>

#define NN 50000
#define NE 1600000
#define HID 128
#define NB 196      // dst buckets: dst>>8 -> 0..195 (256 nodes each)
#define BCAP 12288  // per-bucket LDS edge capacity

typedef _Float16 half8 __attribute__((ext_vector_type(8)));
typedef float floatx4 __attribute__((ext_vector_type(4)));

// ---------------- CSR build: two-level bucket sort (R5-verified) --------------
// ebuf entries are packed (src<<8)|(dst&255): src<2^17, 25 bits total.

__global__ __launch_bounds__(256) void kb_count(const int* __restrict__ dst,
                                                int* __restrict__ gcnt, int E) {
  __shared__ int cnt[NB];
  int tid = threadIdx.x;
  for (int i = tid; i < NB; i += 256) cnt[i] = 0;
  __syncthreads();
  int base = blockIdx.x * 4096;
  for (int i = 0; i < 16; ++i) {
    int e = base + i * 256 + tid;
    if (e < E) atomicAdd(&cnt[dst[e] >> 8], 1);
  }
  __syncthreads();
  for (int i = tid; i < NB; i += 256)
    if (cnt[i]) atomicAdd(&gcnt[i], cnt[i]);
}

__global__ __launch_bounds__(256) void kb_basescan(const int* __restrict__ gcnt,
                                                   int* __restrict__ bbase,
                                                   int* __restrict__ bcur) {
  __shared__ int s[256];
  int tid = threadIdx.x;
  int v = (tid < NB) ? gcnt[tid] : 0;
  s[tid] = v;
  __syncthreads();
  for (int d = 1; d < 256; d <<= 1) {
    int t = (tid >= d) ? s[tid - d] : 0;
    __syncthreads();
    s[tid] += t;
    __syncthreads();
  }
  int incl = s[tid];
  if (tid < NB) {
    bbase[tid] = incl - v;
    bcur[tid] = incl - v;
  }
  if (tid == NB - 1) bbase[NB] = incl;
}

__global__ __launch_bounds__(256) void kb_partition(const int* __restrict__ src,
                                                    const int* __restrict__ dst,
                                                    int* __restrict__ bcur,
                                                    int* __restrict__ ebuf, int E) {
  __shared__ int cnt[NB];
  __shared__ int sbase[NB];
  int tid = threadIdx.x;
  for (int i = tid; i < NB; i += 256) cnt[i] = 0;
  __syncthreads();
  int base = blockIdx.x * 4096;
  int myd[16], mys[16];
#pragma unroll
  for (int i = 0; i < 16; ++i) {
    int e = base + i * 256 + tid;
    if (e < E) {
      myd[i] = dst[e];
      mys[i] = src[e];
      atomicAdd(&cnt[myd[i] >> 8], 1);
    } else {
      myd[i] = -1;
    }
  }
  __syncthreads();
  for (int i = tid; i < NB; i += 256)
    sbase[i] = cnt[i] ? atomicAdd(&bcur[i], cnt[i]) : 0;
  __syncthreads();
  for (int i = tid; i < NB; i += 256) cnt[i] = 0;
  __syncthreads();
#pragma unroll
  for (int i = 0; i < 16; ++i) {
    if (myd[i] >= 0) {
      int b = myd[i] >> 8;
      int r = atomicAdd(&cnt[b], 1);
      ebuf[sbase[b] + r] = (mys[i] << 8) | (myd[i] & 255);
    }
  }
}

__global__ __launch_bounds__(256) void kb_csr(const int* __restrict__ ebuf,
                                              const int* __restrict__ bbase,
                                              int* __restrict__ rs,
                                              int* __restrict__ eidx, int M) {
  __shared__ int cnt[256];
  __shared__ int off[256];
  __shared__ int sbuf[BCAP];
  int tid = threadIdx.x;
  int b = blockIdx.x;
  int lo = bbase[b], hi = bbase[b + 1];
  int n = hi - lo;
  cnt[tid] = 0;
  __syncthreads();
  for (int i = tid; i < n; i += 256) atomicAdd(&cnt[ebuf[lo + i] & 255], 1);
  __syncthreads();
  int v = cnt[tid];
  off[tid] = v;
  __syncthreads();
  for (int d = 1; d < 256; d <<= 1) {
    int t = (tid >= d) ? off[tid - d] : 0;
    __syncthreads();
    off[tid] += t;
    __syncthreads();
  }
  int excl = off[tid] - v;
  int gnode = b * 256 + tid;
  if (gnode < M) rs[gnode] = lo + excl;
  if (b == NB - 1 && tid == 0) rs[M] = bbase[NB];
  __syncthreads();
  cnt[tid] = excl;
  __syncthreads();
  if (n <= BCAP) {
    for (int i = tid; i < n; i += 256) {
      int ed = ebuf[lo + i];
      int r = atomicAdd(&cnt[ed & 255], 1);
      sbuf[r] = ed >> 8;
    }
    __syncthreads();
    for (int i = tid; i < n; i += 256) eidx[lo + i] = sbuf[i];
  } else {
    for (int i = tid; i < n; i += 256) {
      int ed = ebuf[lo + i];
      int r = atomicAdd(&cnt[ed & 255], 1);
      eidx[lo + r] = ed >> 8;
    }
  }
}

// ---------------- fp32 -> fp16 convert (node_feat, once) ----------------

__global__ __launch_bounds__(256) void k_cvt(const float* __restrict__ x,
                                             _Float16* __restrict__ y, int n8) {
  int t = blockIdx.x * 256 + threadIdx.x;
  if (t >= n8) return;
  const float4* x4 = (const float4*)x;
  float4 u = x4[t * 2], v = x4[t * 2 + 1];
  half8 o;
  o[0] = (_Float16)u.x; o[1] = (_Float16)u.y; o[2] = (_Float16)u.z; o[3] = (_Float16)u.w;
  o[4] = (_Float16)v.x; o[5] = (_Float16)v.y; o[6] = (_Float16)v.z; o[7] = (_Float16)v.w;
  ((half8*)y)[t] = o;
}

// ---------------- weight pack: W[k][n] fp32 -> MFMA B-fragment order fp16 ----
// frag idx t = (kb*NCT+ct)*64+lane holds B[kb*32+(lane>>4)*8+j][ct*16+(lane&15)]

__global__ __launch_bounds__(256) void k_pack(const float* __restrict__ W1,
                                              const float* __restrict__ W2,
                                              const float* __restrict__ Wout,
                                              _Float16* __restrict__ wp) {
  int y = blockIdx.y;
  const float* W;
  _Float16* dst;
  int NCT;
  if (y < 3) { W = W1 + (size_t)y * 16384; dst = wp + y * 16384; NCT = 8; }
  else if (y < 6) { W = W2 + (size_t)(y - 3) * 16384; dst = wp + 49152 + (y - 3) * 16384; NCT = 8; }
  else { W = Wout; dst = wp + 98304; NCT = 4; }
  int t = blockIdx.x * 256 + threadIdx.x;
  if (t >= 4 * NCT * 64) return;
  int lane = t & 63;
  int ct = (t >> 6) % NCT;
  int kb = t / (64 * NCT);
  int n = ct * 16 + (lane & 15);
  int k0 = kb * 32 + (lane >> 4) * 8;
  int N = NCT * 16;
#pragma unroll
  for (int j = 0; j < 8; ++j) dst[t * 8 + j] = (_Float16)W[(k0 + j) * N + n];
}

// ---------------- fused agg + GEMM1 + stats (column-pass gather) -------------
// 782 static blocks x 1024 threads (R11: static tile<->CU affinity preserves
// L2 locality). Gather runs in 4 column passes of 64B/row: per-pass table is
// 3.2MB < 4MB/XCD L2, so each XCD streams each quarter ~once (R12: 173MB of
// gather misses at full 256B rows was the dominant HBM traffic).
// Wave layout per pass: 16 edge-slots x 4 lanes; shfl-reduce over slots.

__global__ __launch_bounds__(1024, 8) void k_aggemm1(
    const int* __restrict__ rs, const int* __restrict__ eidx,
    const float* __restrict__ eps, int layer, const _Float16* __restrict__ h,
    const _Float16* __restrict__ wp1, const float* __restrict__ b1L,
    float* __restrict__ csum, float* __restrict__ csq,
    _Float16* __restrict__ x) {
  __shared__ _Float16 As[64 * 136];
  __shared__ float sredS[512];
  __shared__ float sredQ[512];
  const int tid = threadIdx.x;
  const int wid = tid >> 6;
  const int lane = tid & 63;
  const int slot = lane >> 4;     // MFMA quad
  const int c8 = lane & 15;
  const int c8t = tid & 15;
  const int eslot = lane >> 2;    // gather: edge slot (0..15)
  const int col4 = lane & 3;      // gather: half8-column within quarter
  const int rowBase = blockIdx.x * 64;
  const float ep = 1.0f + eps[layer];
  const half8* h8 = (const half8*)h;

  // ---- aggregate in 4 column passes; wave wid owns nodes rowBase+wid*4+i ----
#pragma unroll
  for (int p = 0; p < 4; ++p) {
    const int pc = p * 4;  // half8-column base of this quarter
    for (int i = 0; i < 4; ++i) {
      const int node = rowBase + wid * 4 + i;
      float a0[8] = {0, 0, 0, 0, 0, 0, 0, 0};
      float a1[8] = {0, 0, 0, 0, 0, 0, 0, 0};
      int e0 = 0, e1 = 0;
      if (node < NN) {
        e0 = rs[node];
        e1 = rs[node + 1];
      }
      int e = e0 + eslot;
      for (; e + 16 < e1; e += 32) {
        int s0 = eidx[e];
        int s1 = eidx[e + 16];
        half8 v0 = h8[s0 * 16 + pc + col4];
        half8 v1 = h8[s1 * 16 + pc + col4];
#pragma unroll
        for (int j = 0; j < 8; ++j) {
          a0[j] += (float)v0[j];
          a1[j] += (float)v1[j];
        }
      }
      if (e < e1) {
        half8 v = h8[eidx[e] * 16 + pc + col4];
#pragma unroll
        for (int j = 0; j < 8; ++j) a0[j] += (float)v[j];
      }
#pragma unroll
      for (int j = 0; j < 8; ++j) {
        a0[j] += a1[j];
        a0[j] += __shfl_xor(a0[j], 4);
        a0[j] += __shfl_xor(a0[j], 8);
        a0[j] += __shfl_xor(a0[j], 16);
        a0[j] += __shfl_xor(a0[j], 32);
      }
      if (eslot == 0) {
        half8 o = {0, 0, 0, 0, 0, 0, 0, 0};
        if (node < NN) {
          half8 hv = h8[node * 16 + pc + col4];
#pragma unroll
          for (int j = 0; j < 8; ++j) o[j] = (_Float16)fmaf(ep, (float)hv[j], a0[j]);
        }
        *(half8*)(As + (wid * 4 + i) * 136 + (pc + col4) * 8) = o;
      }
    }
  }
  __syncthreads();

  // ---- GEMM1: wave (rg,cg) does rows rg*16..+15, cols cg*32..+31 ----
  const int rg = wid & 3;
  const int cg = wid >> 2;
  floatx4 acc[2];
  acc[0] = (floatx4){0.f, 0.f, 0.f, 0.f};
  acc[1] = (floatx4){0.f, 0.f, 0.f, 0.f};
  const half8* wp8 = (const half8*)wp1;
#pragma unroll
  for (int kb = 0; kb < 4; ++kb) {
    half8 a = *(const half8*)(As + (rg * 16 + c8) * 136 + kb * 32 + slot * 8);
#pragma unroll
    for (int t = 0; t < 2; ++t) {
      int ct = cg * 2 + t;
      acc[t] = __builtin_amdgcn_mfma_f32_16x16x32_f16(a, wp8[(kb * 8 + ct) * 64 + lane],
                                                      acc[t], 0, 0, 0);
    }
  }
  __syncthreads();  // all waves done reading z in As before overwrite

  // ---- x -> As (fp16, own-wave rows/cols only) + stats partials ----
#pragma unroll
  for (int t = 0; t < 2; ++t) {
    int ct = cg * 2 + t;
    float bv = b1L[ct * 16 + c8];
    float ps = 0.f, pq = 0.f;
#pragma unroll
    for (int reg = 0; reg < 4; ++reg) {
      int row = rg * 16 + slot * 4 + reg;
      float xv = acc[t][reg] + bv;
      As[row * 136 + ct * 16 + c8] = (_Float16)xv;
      if (rowBase + row < NN) {
        ps += xv;
        pq += xv * xv;
      }
    }
    ps += __shfl_xor(ps, 16);
    ps += __shfl_xor(ps, 32);
    pq += __shfl_xor(pq, 16);
    pq += __shfl_xor(pq, 32);
    if (lane < 16) {
      sredS[wid * 32 + t * 16 + lane] = ps;
      sredQ[wid * 32 + t * 16 + lane] = pq;
    }
  }
  __syncthreads();

  // ---- coalesced x store (full 256B rows) + stats atomics ----
  {
    int row = tid >> 4;
    int gr = rowBase + row;
    if (gr < NN) {
      half8 v = *(half8*)(As + row * 136 + c8t * 8);
      *(half8*)(x + (size_t)gr * 128 + c8t * 8) = v;
    }
  }
  if (tid < 128) {
    int c = tid;
    int wbase = (c >> 5) * 4;
    int loc = c & 31;
    float s = sredS[wbase * 32 + loc] + sredS[(wbase + 1) * 32 + loc] +
              sredS[(wbase + 2) * 32 + loc] + sredS[(wbase + 3) * 32 + loc];
    atomicAdd(&csum[c], s);
  } else if (tid < 256) {
    int c = tid - 128;
    int wbase = (c >> 5) * 4;
    int loc = c & 31;
    float q = sredQ[wbase * 32 + loc] + sredQ[(wbase + 1) * 32 + loc] +
              sredQ[(wbase + 2) * 32 + loc] + sredQ[(wbase + 3) * 32 + loc];
    atomicAdd(&csq[c], q);
  }
}

// ---------------- BN + GEMM2 (+ final Wout GEMM when FINAL) — exact R12 ------

template <int FINAL>
__global__ __launch_bounds__(1024, 8) void k_bn_gemm2(
    const _Float16* __restrict__ x, const _Float16* __restrict__ wp2,
    const float* __restrict__ b2L, const float* __restrict__ gammaL,
    const float* __restrict__ betaL, const float* __restrict__ csum,
    const float* __restrict__ csq, _Float16* __restrict__ hout,
    const _Float16* __restrict__ wpo, const float* __restrict__ boutp,
    float* __restrict__ out) {
  __shared__ _Float16 As[64 * 136];
  const int tid = threadIdx.x;
  const int wid = tid >> 6;
  const int lane = tid & 63;
  const int slot = lane >> 4;
  const int c8 = lane & 15;
  const int c8t = tid & 15;
  const int rowBase = blockIdx.x * 64;

  float sc[8], sh[8];
  {
    const float invM = 1.0f / (float)NN;
#pragma unroll
    for (int j = 0; j < 8; ++j) {
      int k = c8t * 8 + j;
      float mu = csum[k] * invM;
      float var = csq[k] * invM - mu * mu;
      float g = gammaL[k] * rsqrtf(var + 1e-5f);
      sc[j] = g;
      sh[j] = fmaf(-mu, g, betaL[k]);
    }
  }
  {
    int row = tid >> 4;
    int gr = rowBase + row;
    half8 v = {0, 0, 0, 0, 0, 0, 0, 0};
    if (gr < NN) {
      v = *(const half8*)(x + (size_t)gr * 128 + c8t * 8);
#pragma unroll
      for (int j = 0; j < 8; ++j)
        v[j] = (_Float16)fmaxf(fmaf((float)v[j], sc[j], sh[j]), 0.f);
    }
    *(half8*)(As + row * 136 + c8t * 8) = v;
  }
  __syncthreads();

  const int rg = wid & 3;
  const int cg = wid >> 2;
  floatx4 acc[2];
  acc[0] = (floatx4){0.f, 0.f, 0.f, 0.f};
  acc[1] = (floatx4){0.f, 0.f, 0.f, 0.f};
  const half8* wp8 = (const half8*)wp2;
#pragma unroll
  for (int kb = 0; kb < 4; ++kb) {
    half8 a = *(const half8*)(As + (rg * 16 + c8) * 136 + kb * 32 + slot * 8);
#pragma unroll
    for (int t = 0; t < 2; ++t) {
      int ct = cg * 2 + t;
      acc[t] = __builtin_amdgcn_mfma_f32_16x16x32_f16(a, wp8[(kb * 8 + ct) * 64 + lane],
                                                      acc[t], 0, 0, 0);
    }
  }
  __syncthreads();  // all waves done reading As before overwrite
#pragma unroll
  for (int t = 0; t < 2; ++t) {
    int ct = cg * 2 + t;
    float bv = b2L[ct * 16 + c8];
#pragma unroll
    for (int reg = 0; reg < 4; ++reg) {
      int row = rg * 16 + slot * 4 + reg;
      As[row * 136 + ct * 16 + c8] = (_Float16)fmaxf(acc[t][reg] + bv, 0.f);
    }
  }
  __syncthreads();

  if (FINAL == 0) {
    int row = tid >> 4;
    int gr = rowBase + row;
    if (gr < NN) {
      half8 v = *(half8*)(As + row * 136 + c8t * 8);
      *(half8*)(hout + (size_t)gr * 128 + c8t * 8) = v;
    }
  } else {
    if (cg < 2) {
      floatx4 acc3[2];
      acc3[0] = (floatx4){0.f, 0.f, 0.f, 0.f};
      acc3[1] = (floatx4){0.f, 0.f, 0.f, 0.f};
      const half8* wo8 = (const half8*)wpo;
#pragma unroll
      for (int kb = 0; kb < 4; ++kb) {
        half8 a = *(const half8*)(As + (rg * 16 + c8) * 136 + kb * 32 + slot * 8);
#pragma unroll
        for (int t = 0; t < 2; ++t) {
          int ct = cg * 2 + t;
          acc3[t] = __builtin_amdgcn_mfma_f32_16x16x32_f16(
              a, wo8[(kb * 4 + ct) * 64 + lane], acc3[t], 0, 0, 0);
        }
      }
#pragma unroll
      for (int t = 0; t < 2; ++t) {
        int ct = cg * 2 + t;
        float bv = boutp[ct * 16 + c8];
#pragma unroll
        for (int reg = 0; reg < 4; ++reg) {
          int gr = rowBase + rg * 16 + slot * 4 + reg;
          if (gr < NN) out[(size_t)gr * 64 + ct * 16 + c8] = acc3[t][reg] + bv;
        }
      }
    }
  }
}

// ---------------- launch ----------------

extern "C" void kernel_launch(void* const* d_in, const int* in_sizes, int n_in,
                              void* d_out, int out_size, void* d_ws, size_t ws_size,
                              hipStream_t stream) {
  const float* node_feat = (const float*)d_in[0];
  const int* src = (const int*)d_in[1];
  const int* dst = (const int*)d_in[2];
  const float* W1 = (const float*)d_in[3];
  const float* b1 = (const float*)d_in[4];
  const float* gamma = (const float*)d_in[5];
  const float* beta = (const float*)d_in[6];
  const float* W2 = (const float*)d_in[7];
  const float* b2 = (const float*)d_in[8];
  const float* eps = (const float*)d_in[9];
  const float* Wout = (const float*)d_in[10];
  const float* bout = (const float*)d_in[11];
  float* out = (float*)d_out;

  // workspace layout (16B-aligned slices)
  int* rs = (int*)d_ws;                  // 50176 ints
  int* gcnt = rs + 50176;                // 256
  int* bbase = gcnt + 256;               // 256
  int* bcur = bbase + 256;               // 256
  float* stats = (float*)(bcur + 256);   // 768 floats: 3 x (csum|csq)
  int* eidx = (int*)(stats + 768);       // NE ints
  _Float16* hb = (_Float16*)(eidx + NE);      // h  (6.4M halves)
  _Float16* xb = hb + (size_t)NN * HID;       // x  (6.4M halves)
  _Float16* wp = xb + (size_t)NN * HID;       // packed weights (106496 halves)
  int* ebuf = (int*)(wp + 106496);            // NE packed ints staging

  hipMemsetAsync(gcnt, 0, (256 * 3 + 768) * sizeof(int), stream);

  k_cvt<<<(NN * HID / 8 + 255) / 256, 256, 0, stream>>>(node_feat, hb, NN * HID / 8);
  k_pack<<<dim3(8, 7), 256, 0, stream>>>(W1, W2, Wout, wp);

  const int partGrid = (NE + 4095) / 4096;
  kb_count<<<partGrid, 256, 0, stream>>>(dst, gcnt, NE);
  kb_basescan<<<1, 256, 0, stream>>>(gcnt, bbase, bcur);
  kb_partition<<<partGrid, 256, 0, stream>>>(src, dst, bcur, ebuf, NE);
  kb_csr<<<NB, 256, 0, stream>>>(ebuf, bbase, rs, eidx, NN);

  const int rowTiles = (NN + 63) / 64;  // 782

  for (int L = 0; L < 3; ++L) {
    float* csum = stats + L * 256;
    float* csq = csum + 128;
    k_aggemm1<<<rowTiles, 1024, 0, stream>>>(
        rs, eidx, eps, L, hb, wp + (size_t)L * 16384, b1 + (size_t)L * HID,
        csum, csq, xb);
    if (L < 2) {
      k_bn_gemm2<0><<<rowTiles, 1024, 0, stream>>>(
          xb, wp + 49152 + (size_t)L * 16384, b2 + (size_t)L * HID,
          gamma + (size_t)L * HID, beta + (size_t)L * HID, csum, csq, hb,
          nullptr, nullptr, nullptr);
    } else {
      k_bn_gemm2<1><<<rowTiles, 1024, 0, stream>>>(
          xb, wp + 49152 + (size_t)L * 16384, b2 + (size_t)L * HID,
          gamma + (size_t)L * HID, beta + (size_t)L * HID, csum, csq, nullptr,
          wp + 98304, bout, out);
    }
  }
}

// Round 14
// 436.586 us; speedup vs baseline: 1.2860x; 1.2860x over previous
//
#include <hip/hip_runtime.h>

#define NN 50000
#define NE 1600000
#define HID 128
#define NB 196      // dst buckets: dst>>8 -> 0..195 (256 nodes each)
#define BCAP 12288  // per-bucket LDS edge capacity

typedef _Float16 half8 __attribute__((ext_vector_type(8)));
typedef float floatx4 __attribute__((ext_vector_type(4)));

// ---------------- fused prep: cvt (fp32->fp16) + weight pack + bucket count --
// Three independent pre-kernels merged into one range-split launch.
// blocks [0,3125): cvt; [3125,3516): count; [3516,3572): pack.

#define CVT_BLK 3125   // 50000*128/8 / 256
#define CNT_BLK 391    // ceil(NE/4096)

__device__ __forceinline__ void pack_one(const float* __restrict__ W1,
                                         const float* __restrict__ W2,
                                         const float* __restrict__ Wout,
                                         _Float16* __restrict__ wp, int y, int t) {
  const float* W;
  _Float16* dstp;
  int NCT;
  if (y < 3) { W = W1 + (size_t)y * 16384; dstp = wp + y * 16384; NCT = 8; }
  else if (y < 6) { W = W2 + (size_t)(y - 3) * 16384; dstp = wp + 49152 + (y - 3) * 16384; NCT = 8; }
  else { W = Wout; dstp = wp + 98304; NCT = 4; }
  if (t >= 4 * NCT * 64) return;
  int lane = t & 63;
  int ct = (t >> 6) % NCT;
  int kb = t / (64 * NCT);
  int n = ct * 16 + (lane & 15);
  int k0 = kb * 32 + (lane >> 4) * 8;
  int N = NCT * 16;
#pragma unroll
  for (int j = 0; j < 8; ++j) dstp[t * 8 + j] = (_Float16)W[(k0 + j) * N + n];
}

__global__ __launch_bounds__(256) void k_prep(
    const float* __restrict__ nf, _Float16* __restrict__ hb,
    const float* __restrict__ W1, const float* __restrict__ W2,
    const float* __restrict__ Wout, _Float16* __restrict__ wp,
    const int* __restrict__ dst, int* __restrict__ gcnt) {
  const int b = blockIdx.x;
  const int tid = threadIdx.x;
  if (b < CVT_BLK) {
    int t = b * 256 + tid;  // < 800000 exactly
    const float4* x4 = (const float4*)nf;
    float4 u = x4[t * 2], v = x4[t * 2 + 1];
    half8 o;
    o[0] = (_Float16)u.x; o[1] = (_Float16)u.y; o[2] = (_Float16)u.z; o[3] = (_Float16)u.w;
    o[4] = (_Float16)v.x; o[5] = (_Float16)v.y; o[6] = (_Float16)v.z; o[7] = (_Float16)v.w;
    ((half8*)hb)[t] = o;
  } else if (b < CVT_BLK + CNT_BLK) {
    __shared__ int cnt[NB];
    for (int i = tid; i < NB; i += 256) cnt[i] = 0;
    __syncthreads();
    int base = (b - CVT_BLK) * 4096;
    for (int i = 0; i < 16; ++i) {
      int e = base + i * 256 + tid;
      if (e < NE) atomicAdd(&cnt[dst[e] >> 8], 1);
    }
    __syncthreads();
    for (int i = tid; i < NB; i += 256)
      if (cnt[i]) atomicAdd(&gcnt[i], cnt[i]);
  } else {
    int bb = b - (CVT_BLK + CNT_BLK);
    pack_one(W1, W2, Wout, wp, bb >> 3, ((bb & 7) << 8) | tid);
  }
}

// ---------------- CSR build (R13 packed ebuf: (src<<8)|(dst&255)) ------------

__global__ __launch_bounds__(256) void kb_basescan(const int* __restrict__ gcnt,
                                                   int* __restrict__ bbase,
                                                   int* __restrict__ bcur) {
  __shared__ int s[256];
  int tid = threadIdx.x;
  int v = (tid < NB) ? gcnt[tid] : 0;
  s[tid] = v;
  __syncthreads();
  for (int d = 1; d < 256; d <<= 1) {
    int t = (tid >= d) ? s[tid - d] : 0;
    __syncthreads();
    s[tid] += t;
    __syncthreads();
  }
  int incl = s[tid];
  if (tid < NB) {
    bbase[tid] = incl - v;
    bcur[tid] = incl - v;
  }
  if (tid == NB - 1) bbase[NB] = incl;
}

__global__ __launch_bounds__(256) void kb_partition(const int* __restrict__ src,
                                                    const int* __restrict__ dst,
                                                    int* __restrict__ bcur,
                                                    int* __restrict__ ebuf, int E) {
  __shared__ int cnt[NB];
  __shared__ int sbase[NB];
  int tid = threadIdx.x;
  for (int i = tid; i < NB; i += 256) cnt[i] = 0;
  __syncthreads();
  int base = blockIdx.x * 4096;
  int myd[16], mys[16];
#pragma unroll
  for (int i = 0; i < 16; ++i) {
    int e = base + i * 256 + tid;
    if (e < E) {
      myd[i] = dst[e];
      mys[i] = src[e];
      atomicAdd(&cnt[myd[i] >> 8], 1);
    } else {
      myd[i] = -1;
    }
  }
  __syncthreads();
  for (int i = tid; i < NB; i += 256)
    sbase[i] = cnt[i] ? atomicAdd(&bcur[i], cnt[i]) : 0;
  __syncthreads();
  for (int i = tid; i < NB; i += 256) cnt[i] = 0;
  __syncthreads();
#pragma unroll
  for (int i = 0; i < 16; ++i) {
    if (myd[i] >= 0) {
      int b = myd[i] >> 8;
      int r = atomicAdd(&cnt[b], 1);
      ebuf[sbase[b] + r] = (mys[i] << 8) | (myd[i] & 255);
    }
  }
}

__global__ __launch_bounds__(256) void kb_csr(const int* __restrict__ ebuf,
                                              const int* __restrict__ bbase,
                                              int* __restrict__ rs,
                                              int* __restrict__ eidx, int M) {
  __shared__ int cnt[256];
  __shared__ int off[256];
  __shared__ int sbuf[BCAP];
  int tid = threadIdx.x;
  int b = blockIdx.x;
  int lo = bbase[b], hi = bbase[b + 1];
  int n = hi - lo;
  cnt[tid] = 0;
  __syncthreads();
  for (int i = tid; i < n; i += 256) atomicAdd(&cnt[ebuf[lo + i] & 255], 1);
  __syncthreads();
  int v = cnt[tid];
  off[tid] = v;
  __syncthreads();
  for (int d = 1; d < 256; d <<= 1) {
    int t = (tid >= d) ? off[tid - d] : 0;
    __syncthreads();
    off[tid] += t;
    __syncthreads();
  }
  int excl = off[tid] - v;
  int gnode = b * 256 + tid;
  if (gnode < M) rs[gnode] = lo + excl;
  if (b == NB - 1 && tid == 0) rs[M] = bbase[NB];
  __syncthreads();
  cnt[tid] = excl;
  __syncthreads();
  if (n <= BCAP) {
    for (int i = tid; i < n; i += 256) {
      int ed = ebuf[lo + i];
      int r = atomicAdd(&cnt[ed & 255], 1);
      sbuf[r] = ed >> 8;
    }
    __syncthreads();
    for (int i = tid; i < n; i += 256) eidx[lo + i] = sbuf[i];
  } else {
    for (int i = tid; i < n; i += 256) {
      int ed = ebuf[lo + i];
      int r = atomicAdd(&cnt[ed & 255], 1);
      eidx[lo + r] = ed >> 8;
    }
  }
}

// ---------------- fused agg + GEMM1 + stats (exact R12 — best measured) ------
// 782 static blocks x 1024 threads; static tile<->CU affinity (R11 lesson).
// Gather: full 256B rows, 4-chain ILP (R13's column passes regressed: short
// loops -> overhead-bound). Measured wall: ~3 TB/s for random 256B gathers
// over a 12.8MB table on 8 XCDs (R7/R10/R12 concordant; not latency-bound).

__global__ __launch_bounds__(1024, 8) void k_aggemm1(
    const int* __restrict__ rs, const int* __restrict__ eidx,
    const float* __restrict__ eps, int layer, const _Float16* __restrict__ h,
    const _Float16* __restrict__ wp1, const float* __restrict__ b1L,
    float* __restrict__ csum, float* __restrict__ csq,
    _Float16* __restrict__ x) {
  __shared__ _Float16 As[64 * 136];
  __shared__ float sredS[512];
  __shared__ float sredQ[512];
  const int tid = threadIdx.x;
  const int wid = tid >> 6;
  const int lane = tid & 63;
  const int slot = lane >> 4;
  const int c8 = lane & 15;
  const int c8t = tid & 15;
  const int rowBase = blockIdx.x * 64;
  const float ep = 1.0f + eps[layer];
  const half8* h8 = (const half8*)h;

  for (int i = 0; i < 4; ++i) {
    const int node = rowBase + wid * 4 + i;
    float a0[8] = {0, 0, 0, 0, 0, 0, 0, 0};
    float a1[8] = {0, 0, 0, 0, 0, 0, 0, 0};
    float a2[8] = {0, 0, 0, 0, 0, 0, 0, 0};
    float a3[8] = {0, 0, 0, 0, 0, 0, 0, 0};
    int e0 = 0, e1 = 0;
    if (node < NN) {
      e0 = rs[node];
      e1 = rs[node + 1];
    }
    int e = e0 + slot;
    for (; e + 12 < e1; e += 16) {
      int s0 = eidx[e];
      int s1 = eidx[e + 4];
      int s2 = eidx[e + 8];
      int s3 = eidx[e + 12];
      half8 v0 = h8[s0 * 16 + c8];
      half8 v1 = h8[s1 * 16 + c8];
      half8 v2 = h8[s2 * 16 + c8];
      half8 v3 = h8[s3 * 16 + c8];
#pragma unroll
      for (int j = 0; j < 8; ++j) {
        a0[j] += (float)v0[j];
        a1[j] += (float)v1[j];
        a2[j] += (float)v2[j];
        a3[j] += (float)v3[j];
      }
    }
    for (; e < e1; e += 4) {
      half8 v = h8[eidx[e] * 16 + c8];
#pragma unroll
      for (int j = 0; j < 8; ++j) a0[j] += (float)v[j];
    }
#pragma unroll
    for (int j = 0; j < 8; ++j) {
      a0[j] += a1[j] + a2[j] + a3[j];
      a0[j] += __shfl_xor(a0[j], 16);
      a0[j] += __shfl_xor(a0[j], 32);
    }
    if (slot == 0) {
      half8 o = {0, 0, 0, 0, 0, 0, 0, 0};
      if (node < NN) {
        half8 hv = h8[node * 16 + c8];
#pragma unroll
        for (int j = 0; j < 8; ++j) o[j] = (_Float16)fmaf(ep, (float)hv[j], a0[j]);
      }
      *(half8*)(As + (wid * 4 + i) * 136 + c8 * 8) = o;
    }
  }
  __syncthreads();

  const int rg = wid & 3;
  const int cg = wid >> 2;
  floatx4 acc[2];
  acc[0] = (floatx4){0.f, 0.f, 0.f, 0.f};
  acc[1] = (floatx4){0.f, 0.f, 0.f, 0.f};
  const half8* wp8 = (const half8*)wp1;
#pragma unroll
  for (int kb = 0; kb < 4; ++kb) {
    half8 a = *(const half8*)(As + (rg * 16 + c8) * 136 + kb * 32 + slot * 8);
#pragma unroll
    for (int t = 0; t < 2; ++t) {
      int ct = cg * 2 + t;
      acc[t] = __builtin_amdgcn_mfma_f32_16x16x32_f16(a, wp8[(kb * 8 + ct) * 64 + lane],
                                                      acc[t], 0, 0, 0);
    }
  }
  __syncthreads();

#pragma unroll
  for (int t = 0; t < 2; ++t) {
    int ct = cg * 2 + t;
    float bv = b1L[ct * 16 + c8];
    float ps = 0.f, pq = 0.f;
#pragma unroll
    for (int reg = 0; reg < 4; ++reg) {
      int row = rg * 16 + slot * 4 + reg;
      float xv = acc[t][reg] + bv;
      As[row * 136 + ct * 16 + c8] = (_Float16)xv;
      if (rowBase + row < NN) {
        ps += xv;
        pq += xv * xv;
      }
    }
    ps += __shfl_xor(ps, 16);
    ps += __shfl_xor(ps, 32);
    pq += __shfl_xor(pq, 16);
    pq += __shfl_xor(pq, 32);
    if (lane < 16) {
      sredS[wid * 32 + t * 16 + lane] = ps;
      sredQ[wid * 32 + t * 16 + lane] = pq;
    }
  }
  __syncthreads();

  {
    int row = tid >> 4;
    int gr = rowBase + row;
    if (gr < NN) {
      half8 v = *(half8*)(As + row * 136 + c8t * 8);
      *(half8*)(x + (size_t)gr * 128 + c8t * 8) = v;
    }
  }
  if (tid < 128) {
    int c = tid;
    int wbase = (c >> 5) * 4;
    int loc = c & 31;
    float s = sredS[wbase * 32 + loc] + sredS[(wbase + 1) * 32 + loc] +
              sredS[(wbase + 2) * 32 + loc] + sredS[(wbase + 3) * 32 + loc];
    atomicAdd(&csum[c], s);
  } else if (tid < 256) {
    int c = tid - 128;
    int wbase = (c >> 5) * 4;
    int loc = c & 31;
    float q = sredQ[wbase * 32 + loc] + sredQ[(wbase + 1) * 32 + loc] +
              sredQ[(wbase + 2) * 32 + loc] + sredQ[(wbase + 3) * 32 + loc];
    atomicAdd(&csq[c], q);
  }
}

// ---------------- BN + GEMM2 (+ final Wout GEMM when FINAL) — exact R12 ------

template <int FINAL>
__global__ __launch_bounds__(1024, 8) void k_bn_gemm2(
    const _Float16* __restrict__ x, const _Float16* __restrict__ wp2,
    const float* __restrict__ b2L, const float* __restrict__ gammaL,
    const float* __restrict__ betaL, const float* __restrict__ csum,
    const float* __restrict__ csq, _Float16* __restrict__ hout,
    const _Float16* __restrict__ wpo, const float* __restrict__ boutp,
    float* __restrict__ out) {
  __shared__ _Float16 As[64 * 136];
  const int tid = threadIdx.x;
  const int wid = tid >> 6;
  const int lane = tid & 63;
  const int slot = lane >> 4;
  const int c8 = lane & 15;
  const int c8t = tid & 15;
  const int rowBase = blockIdx.x * 64;

  float sc[8], sh[8];
  {
    const float invM = 1.0f / (float)NN;
#pragma unroll
    for (int j = 0; j < 8; ++j) {
      int k = c8t * 8 + j;
      float mu = csum[k] * invM;
      float var = csq[k] * invM - mu * mu;
      float g = gammaL[k] * rsqrtf(var + 1e-5f);
      sc[j] = g;
      sh[j] = fmaf(-mu, g, betaL[k]);
    }
  }
  {
    int row = tid >> 4;
    int gr = rowBase + row;
    half8 v = {0, 0, 0, 0, 0, 0, 0, 0};
    if (gr < NN) {
      v = *(const half8*)(x + (size_t)gr * 128 + c8t * 8);
#pragma unroll
      for (int j = 0; j < 8; ++j)
        v[j] = (_Float16)fmaxf(fmaf((float)v[j], sc[j], sh[j]), 0.f);
    }
    *(half8*)(As + row * 136 + c8t * 8) = v;
  }
  __syncthreads();

  const int rg = wid & 3;
  const int cg = wid >> 2;
  floatx4 acc[2];
  acc[0] = (floatx4){0.f, 0.f, 0.f, 0.f};
  acc[1] = (floatx4){0.f, 0.f, 0.f, 0.f};
  const half8* wp8 = (const half8*)wp2;
#pragma unroll
  for (int kb = 0; kb < 4; ++kb) {
    half8 a = *(const half8*)(As + (rg * 16 + c8) * 136 + kb * 32 + slot * 8);
#pragma unroll
    for (int t = 0; t < 2; ++t) {
      int ct = cg * 2 + t;
      acc[t] = __builtin_amdgcn_mfma_f32_16x16x32_f16(a, wp8[(kb * 8 + ct) * 64 + lane],
                                                      acc[t], 0, 0, 0);
    }
  }
  __syncthreads();
#pragma unroll
  for (int t = 0; t < 2; ++t) {
    int ct = cg * 2 + t;
    float bv = b2L[ct * 16 + c8];
#pragma unroll
    for (int reg = 0; reg < 4; ++reg) {
      int row = rg * 16 + slot * 4 + reg;
      As[row * 136 + ct * 16 + c8] = (_Float16)fmaxf(acc[t][reg] + bv, 0.f);
    }
  }
  __syncthreads();

  if (FINAL == 0) {
    int row = tid >> 4;
    int gr = rowBase + row;
    if (gr < NN) {
      half8 v = *(half8*)(As + row * 136 + c8t * 8);
      *(half8*)(hout + (size_t)gr * 128 + c8t * 8) = v;
    }
  } else {
    if (cg < 2) {
      floatx4 acc3[2];
      acc3[0] = (floatx4){0.f, 0.f, 0.f, 0.f};
      acc3[1] = (floatx4){0.f, 0.f, 0.f, 0.f};
      const half8* wo8 = (const half8*)wpo;
#pragma unroll
      for (int kb = 0; kb < 4; ++kb) {
        half8 a = *(const half8*)(As + (rg * 16 + c8) * 136 + kb * 32 + slot * 8);
#pragma unroll
        for (int t = 0; t < 2; ++t) {
          int ct = cg * 2 + t;
          acc3[t] = __builtin_amdgcn_mfma_f32_16x16x32_f16(
              a, wo8[(kb * 4 + ct) * 64 + lane], acc3[t], 0, 0, 0);
        }
      }
#pragma unroll
      for (int t = 0; t < 2; ++t) {
        int ct = cg * 2 + t;
        float bv = boutp[ct * 16 + c8];
#pragma unroll
        for (int reg = 0; reg < 4; ++reg) {
          int gr = rowBase + rg * 16 + slot * 4 + reg;
          if (gr < NN) out[(size_t)gr * 64 + ct * 16 + c8] = acc3[t][reg] + bv;
        }
      }
    }
  }
}

// ---------------- launch ----------------

extern "C" void kernel_launch(void* const* d_in, const int* in_sizes, int n_in,
                              void* d_out, int out_size, void* d_ws, size_t ws_size,
                              hipStream_t stream) {
  const float* node_feat = (const float*)d_in[0];
  const int* src = (const int*)d_in[1];
  const int* dst = (const int*)d_in[2];
  const float* W1 = (const float*)d_in[3];
  const float* b1 = (const float*)d_in[4];
  const float* gamma = (const float*)d_in[5];
  const float* beta = (const float*)d_in[6];
  const float* W2 = (const float*)d_in[7];
  const float* b2 = (const float*)d_in[8];
  const float* eps = (const float*)d_in[9];
  const float* Wout = (const float*)d_in[10];
  const float* bout = (const float*)d_in[11];
  float* out = (float*)d_out;

  // workspace layout (16B-aligned slices)
  int* rs = (int*)d_ws;                  // 50176 ints
  int* gcnt = rs + 50176;                // 256
  int* bbase = gcnt + 256;               // 256
  int* bcur = bbase + 256;               // 256
  float* stats = (float*)(bcur + 256);   // 768 floats: 3 x (csum|csq)
  int* eidx = (int*)(stats + 768);       // NE ints
  _Float16* hb = (_Float16*)(eidx + NE);      // h  (6.4M halves)
  _Float16* xb = hb + (size_t)NN * HID;       // x  (6.4M halves)
  _Float16* wp = xb + (size_t)NN * HID;       // packed weights (106496 halves)
  int* ebuf = (int*)(wp + 106496);            // NE packed ints staging

  hipMemsetAsync(gcnt, 0, (256 * 3 + 768) * sizeof(int), stream);

  // fused cvt + count + pack
  k_prep<<<CVT_BLK + CNT_BLK + 56, 256, 0, stream>>>(node_feat, hb, W1, W2, Wout,
                                                     wp, dst, gcnt);
  kb_basescan<<<1, 256, 0, stream>>>(gcnt, bbase, bcur);
  kb_partition<<<CNT_BLK, 256, 0, stream>>>(src, dst, bcur, ebuf, NE);
  kb_csr<<<NB, 256, 0, stream>>>(ebuf, bbase, rs, eidx, NN);

  const int rowTiles = (NN + 63) / 64;  // 782

  for (int L = 0; L < 3; ++L) {
    float* csum = stats + L * 256;
    float* csq = csum + 128;
    k_aggemm1<<<rowTiles, 1024, 0, stream>>>(
        rs, eidx, eps, L, hb, wp + (size_t)L * 16384, b1 + (size_t)L * HID,
        csum, csq, xb);
    if (L < 2) {
      k_bn_gemm2<0><<<rowTiles, 1024, 0, stream>>>(
          xb, wp + 49152 + (size_t)L * 16384, b2 + (size_t)L * HID,
          gamma + (size_t)L * HID, beta + (size_t)L * HID, csum, csq, hb,
          nullptr, nullptr, nullptr);
    } else {
      k_bn_gemm2<1><<<rowTiles, 1024, 0, stream>>>(
          xb, wp + 49152 + (size_t)L * 16384, b2 + (size_t)L * HID,
          gamma + (size_t)L * HID, beta + (size_t)L * HID, csum, csq, nullptr,
          wp + 98304, bout, out);
    }
  }
}